// Round 9
// baseline (284.632 us; speedup 1.0000x reference)
//
#include <hip/hip_runtime.h>
#include <hip/hip_bf16.h>

typedef unsigned long long u64;
typedef unsigned int u32;

#define NTOT    54560   // anchors per batch (r + i)
#define NMOD    27280   // anchors per modality
#define BATCH   16
#define KPAD    1024
#define MAXD    1000
#define NBIN    16384   // score-bits >> 16
#define CAND    6144    // LDS candidate cap (u64, 48KB)

struct Ptrs { const float* p[30]; };

// ---------------- workspace layout (16B aligned) ----------------
constexpr size_t SZ_KEY   = (size_t)BATCH * NTOT * 8;        // 6.98 MB
constexpr size_t SZ_TRAW  = (size_t)BATCH * KPAD * 16;
constexpr size_t SZ_TOFF  = (size_t)BATCH * KPAD * 16;
constexpr size_t SZ_T1    = (size_t)BATCH * KPAD * 4;
constexpr size_t SZ_VALID = (size_t)BATCH * 32 * 4;
constexpr size_t SZ_MASK  = (size_t)BATCH * KPAD * 32 * 4;   // 2 MB

constexpr size_t OFF_KEY    = 0;
constexpr size_t OFF_TRAW   = OFF_KEY   + SZ_KEY;
constexpr size_t OFF_TOFF   = OFF_TRAW  + SZ_TRAW;
constexpr size_t OFF_TAREA  = OFF_TOFF  + SZ_TOFF;
constexpr size_t OFF_TSCORE = OFF_TAREA + SZ_T1;
constexpr size_t OFF_TCLSF  = OFF_TSCORE+ SZ_T1;
constexpr size_t OFF_VALID  = OFF_TCLSF + SZ_T1;
constexpr size_t OFF_MASK   = OFF_VALID + SZ_VALID;

__device__ inline void level_of(int nm, int& l, int& pos, int& w, int& s, int& hw) {
    if (nm < 20480)      { l = 0; pos = nm;         w = 160; s = 8;   hw = 20480; }
    else if (nm < 25600) { l = 1; pos = nm - 20480; w = 80;  s = 16;  hw = 5120; }
    else if (nm < 26880) { l = 2; pos = nm - 25600; w = 40;  s = 32;  hw = 1280; }
    else if (nm < 27200) { l = 3; pos = nm - 26880; w = 20;  s = 64;  hw = 320; }
    else                 { l = 4; pos = nm - 27200; w = 10;  s = 128; hw = 80; }
}

__device__ inline float sigm(float x) { return 1.0f / (1.0f + expf(-x)); }

// async global->LDS DMA, 16B per lane; LDS dest = uniform base + lane*16
__device__ inline void ld_lds16(const float* g, float* l) {
    __builtin_amdgcn_global_load_lds(
        (const __attribute__((address_space(1))) void*)g,
        (__attribute__((address_space(3))) void*)l, 16, 0, 0);
}

// ---------------- kernel 1: decode (LDS-staged levels 0-1 + quad-split tail) ----------------
__global__ __launch_bounds__(256)
void decode_kernel(Ptrs ptrs, u64* __restrict__ keyAll) {
    __shared__ float lds[21 * 1024];    // 84KB (unused by tail blocks)
    int cc = blockIdx.x;                // 0..49 LDS path, 50..63 tail
    int b = blockIdx.y;

    if (cc >= 50) {
        int t = (cc - 50) * 256 + threadIdx.x;   // 0..3359
        if (t >= 3360) return;
        int mod = t / 1680;
        int tm = t % 1680;
        int q = t & 3;
        int nm = 25600 + (tm & ~3);
        int l, pos, w, s, hw;
        level_of(nm, l, pos, w, s, hw);
        (void)w; (void)s;
        const float* clsP = ptrs.p[mod * 15 + l];
        const float* cntP = ptrs.p[mod * 15 + 5 + l];
        const float4* cb = (const float4*)(clsP + (size_t)b * 20 * hw + pos);
        int hw4 = hw >> 2;
        int c0 = q * 5;
        float4 v[5];
        #pragma unroll
        for (int c = 0; c < 5; ++c) v[c] = cb[(size_t)(c0 + c) * hw4];
        float4 cv = *(const float4*)(cntP + (size_t)b * hw + pos);
        float4 mx = v[0];
        #pragma unroll
        for (int c = 1; c < 5; ++c) {
            mx.x = fmaxf(mx.x, v[c].x); mx.y = fmaxf(mx.y, v[c].y);
            mx.z = fmaxf(mx.z, v[c].z); mx.w = fmaxf(mx.w, v[c].w);
        }
        mx.x = fmaxf(mx.x, __shfl_xor(mx.x, 1));
        mx.y = fmaxf(mx.y, __shfl_xor(mx.y, 1));
        mx.z = fmaxf(mx.z, __shfl_xor(mx.z, 1));
        mx.w = fmaxf(mx.w, __shfl_xor(mx.w, 1));
        mx.x = fmaxf(mx.x, __shfl_xor(mx.x, 2));
        mx.y = fmaxf(mx.y, __shfl_xor(mx.y, 2));
        mx.z = fmaxf(mx.z, __shfl_xor(mx.z, 2));
        mx.w = fmaxf(mx.w, __shfl_xor(mx.w, 2));
        float ma = (q & 1) ? ((q & 2) ? mx.w : mx.y) : ((q & 2) ? mx.z : mx.x);
        float ca = (q & 1) ? ((q & 2) ? cv.w : cv.y) : ((q & 2) ? cv.z : cv.x);
        u32 sb = __float_as_uint(sqrtf(__fmul_rn(sigm(ma), sigm(ca))));
        int n = mod * NMOD + nm + q;
        keyAll[(size_t)b * NTOT + n] = ((u64)sb << 16) | (u64)(65535 - n);
        return;
    }

    int mod = cc / 25, c = cc % 25;
    int l     = (c < 20) ? 0 : 1;
    int hw    = (c < 20) ? 20480 : 5120;
    int pos0  = (c < 20) ? c * 1024 : (c - 20) * 1024;
    int nmb   = (l == 0) ? pos0 : 20480 + pos0;
    const float* clsP = ptrs.p[mod * 15 + l];
    const float* cntP = ptrs.p[mod * 15 + 5 + l];
    int wave = threadIdx.x >> 6, lane = threadIdx.x & 63;

    const float* cbase = clsP + (size_t)b * 20 * hw + pos0 + wave * 256 + lane * 4;
    float* dbase = lds + wave * 256;
    #pragma unroll
    for (int ch = 0; ch < 20; ++ch)
        ld_lds16(cbase + (size_t)ch * hw, dbase + ch * 1024);
    ld_lds16(cntP + (size_t)b * hw + pos0 + wave * 256 + lane * 4, dbase + 20 * 1024);
    __syncthreads();

    int t = threadIdx.x;
    const float4* l4 = (const float4*)lds;
    float4 mx = l4[t];
    #pragma unroll
    for (int ch = 1; ch < 20; ++ch) {
        float4 v = l4[ch * 256 + t];
        mx.x = fmaxf(mx.x, v.x); mx.y = fmaxf(mx.y, v.y);
        mx.z = fmaxf(mx.z, v.z); mx.w = fmaxf(mx.w, v.w);
    }
    float4 cv = l4[20 * 256 + t];

    int n = mod * NMOD + nmb + t * 4;
    u32 s0 = __float_as_uint(sqrtf(__fmul_rn(sigm(mx.x), sigm(cv.x))));
    u32 s1 = __float_as_uint(sqrtf(__fmul_rn(sigm(mx.y), sigm(cv.y))));
    u32 s2 = __float_as_uint(sqrtf(__fmul_rn(sigm(mx.z), sigm(cv.z))));
    u32 s3 = __float_as_uint(sqrtf(__fmul_rn(sigm(mx.w), sigm(cv.w))));
    ulonglong2* ka2 = (ulonglong2*)(keyAll + (size_t)b * NTOT + n);
    ulonglong2 k01, k23;
    k01.x = ((u64)s0 << 16) | (u64)(65535 - n);
    k01.y = ((u64)s1 << 16) | (u64)(65535 - (n + 1));
    k23.x = ((u64)s2 << 16) | (u64)(65535 - (n + 2));
    k23.y = ((u64)s3 << 16) | (u64)(65535 - (n + 3));
    ka2[0] = k01; ka2[1] = k23;
}

// ---------------- kernel 2: fused select + bucket-sort + gather ----------------
// hist -> B1 + prefix writeback -> scatter (bin-ordered) -> in-bin rank fixup
// -> sorted top-1000 in LDS -> gather inputs -> maxc reduce -> write all per-topk arrays.
__global__ __launch_bounds__(1024)
void select_gather_kernel(Ptrs ptrs, const u64* __restrict__ keyAll,
                          float4* __restrict__ traw, float4* __restrict__ toff,
                          float* __restrict__ tarea, float* __restrict__ tscore,
                          float* __restrict__ tclsf, u32* __restrict__ validwords) {
    #pragma clang fp contract(off)
    int b = blockIdx.x, tid = threadIdx.x;
    int lane = tid & 63, wid = tid >> 6;
    __shared__ u32 shist[NBIN];        // 64KB: counts -> prefixes -> segment ends
    __shared__ u64 scand[CAND];        // 48KB bin-ordered candidates
    __shared__ u64 stopk[KPAD];        // 8KB sorted top keys
    __shared__ u32 warep[16];
    __shared__ int sB1;
    __shared__ float sred[16];
    __shared__ float smaxc;

    #pragma unroll
    for (int j = 0; j < NBIN / 1024; ++j) shist[tid + j * 1024] = 0u;
    __syncthreads();

    const u64* keys = keyAll + (size_t)b * NTOT;
    const u64 SENT = ~0ull;
    // phase 1: LDS histogram
    for (int n0 = 0; n0 < NTOT; n0 += 8192) {
        u64 kk[8];
        #pragma unroll
        for (int r = 0; r < 8; ++r) {
            int idx = n0 + r * 1024 + tid;
            kk[r] = (idx < NTOT) ? keys[idx] : SENT;
        }
        #pragma unroll
        for (int r = 0; r < 8; ++r)
            if (kk[r] != SENT) atomicAdd(&shist[(u32)(kk[r] >> 32)], 1u);
    }
    __syncthreads();

    // phase 2: reverse scan -> B1; then write P[bin] (keys in bins > bin) back into shist
    u32 loc[16]; u32 sum = 0;
    #pragma unroll
    for (int j = 0; j < 16; ++j) { loc[j] = shist[NBIN - 1 - (tid * 16 + j)]; sum += loc[j]; }
    u32 v = sum;
    #pragma unroll
    for (int off = 1; off < 64; off <<= 1) {
        u32 t2 = (u32)__shfl_up((int)v, off);
        if (lane >= off) v += t2;
    }
    if (lane == 63) warep[wid] = v;
    __syncthreads();
    if (tid < 16) {
        u32 p = warep[tid];
        #pragma unroll
        for (int off = 1; off < 16; off <<= 1) {
            u32 t2 = (u32)__shfl_up((int)p, off);
            if (tid >= off) p += t2;
        }
        warep[tid] = p;
    }
    __syncthreads();
    u32 incl = v + (wid ? warep[wid - 1] : 0u);
    u32 excl = incl - sum;
    if (excl < (u32)MAXD && incl >= (u32)MAXD) {
        u32 c = excl;
        #pragma unroll
        for (int j = 0; j < 16; ++j) {
            c += loc[j];
            if (c >= (u32)MAXD) { sB1 = NBIN - 1 - (tid * 16 + j); break; }
        }
    }
    // prefix writeback (reads of shist all completed before the warep barriers)
    u32 run = excl;
    #pragma unroll
    for (int j = 0; j < 16; ++j) {
        int bin = NBIN - 1 - (tid * 16 + j);
        shist[bin] = run;
        run += loc[j];
    }
    __syncthreads();
    int B1 = sB1;

    // phase 3: scatter candidates to bin-ordered positions
    for (int n0 = 0; n0 < NTOT; n0 += 8192) {
        u64 kk[8];
        #pragma unroll
        for (int r = 0; r < 8; ++r) {
            int idx = n0 + r * 1024 + tid;
            kk[r] = (idx < NTOT) ? keys[idx] : 0ull;   // real keys never 0
        }
        #pragma unroll
        for (int r = 0; r < 8; ++r) {
            if (kk[r] != 0ull && (int)(kk[r] >> 32) >= B1) {
                u32 p = atomicAdd(&shist[(u32)(kk[r] >> 32)], 1u);
                if (p < CAND) scand[p] = kk[r];
            }
        }
    }
    __syncthreads();
    int Ctot = min((int)shist[B1], CAND);

    // phase 4: in-bin rank fixup -> exact sorted positions
    for (int i = tid; i < Ctot; i += 1024) {
        u64 ki = scand[i];
        int bin = (int)(ki >> 32);
        int st = (int)shist[bin + 1];              // P[bin] = segment start
        int en = min((int)shist[bin], Ctot);       // segment end
        int pos = st;
        for (int j = st; j < en; ++j) pos += (scand[j] > ki) ? 1 : 0;
        if (pos < MAXD) stopk[pos] = ki;
    }
    __syncthreads();

    // phase 5: gather winner data (thread i = winner i)
    float4 bx = make_float4(0.f, 0.f, 0.f, 0.f);
    float score = 0.f, clsf = 0.f;
    int valid = 0;
    if (tid < MAXD) {
        u64 key = stopk[tid];
        int n = 65535 - (int)(key & 0xFFFFull);
        score = __uint_as_float((u32)(key >> 16));
        int mod = (n >= NMOD) ? 1 : 0;
        int nm = n - mod * NMOD;
        int l, pos, w, s, hw;
        level_of(nm, l, pos, w, s, hw);
        const float* clsP = ptrs.p[mod * 15 + l];
        const float* regP = ptrs.p[mod * 15 + 10 + l];
        const float* cbp = clsP + (size_t)b * 20 * hw + pos;
        const float* rbp = regP + (size_t)b * 4 * hw + pos;
        float cl[20];
        #pragma unroll
        for (int c = 0; c < 20; ++c) cl[c] = cbp[(size_t)c * hw];
        float r0 = rbp[0], r1 = rbp[(size_t)hw], r2 = rbp[(size_t)2 * hw], r3 = rbp[(size_t)3 * hw];
        float best = -1.0f; int bi = 0;
        #pragma unroll
        for (int c = 0; c < 20; ++c) {
            float p = sigm(cl[c]);
            if (p > best) { best = p; bi = c; }
        }
        clsf = (float)(bi + 1);
        int xi = pos % w, yi = pos / w;
        float cx = (float)(xi * s + (s >> 1));
        float cy = (float)(yi * s + (s >> 1));
        bx.x = cx - r0; bx.y = cy - r1; bx.z = cx + r2; bx.w = cy + r3;
        valid = (score >= 0.05f) ? 1 : 0;
    }

    // maxc block reduction (ref: max over where(valid, boxes, 0) -> baseline 0)
    float contrib = valid ? fmaxf(0.0f, fmaxf(fmaxf(bx.x, bx.y), fmaxf(bx.z, bx.w))) : 0.0f;
    float red = contrib;
    #pragma unroll
    for (int off = 32; off > 0; off >>= 1) red = fmaxf(red, __shfl_down(red, off));
    if (lane == 0) sred[wid] = red;
    // validwords: wave wid covers winners [64*wid, 64*wid+64)
    u64 ball = __ballot(valid != 0);
    if (lane == 0) {
        validwords[b * 32 + 2 * wid]     = (u32)(ball & 0xFFFFFFFFull);
        validwords[b * 32 + 2 * wid + 1] = (u32)(ball >> 32);
    }
    __syncthreads();
    if (tid == 0) {
        float m = sred[0];
        #pragma unroll
        for (int i = 1; i < 16; ++i) m = fmaxf(m, sred[i]);
        smaxc = m;
    }
    __syncthreads();

    // phase 6: offset boxes + areas (bit-identical expressions) + write all arrays
    float m1 = smaxc + 1.0f;
    float o = __fmul_rn(clsf, m1);
    float4 ob;
    ob.x = __fadd_rn(bx.x, o); ob.y = __fadd_rn(bx.y, o);
    ob.z = __fadd_rn(bx.z, o); ob.w = __fadd_rn(bx.w, o);
    float dw = ob.z - ob.x + 1.0f;
    float dh = ob.w - ob.y + 1.0f;
    size_t oo = (size_t)b * KPAD + tid;
    traw[oo] = bx; toff[oo] = ob; tarea[oo] = __fmul_rn(dw, dh);
    tscore[oo] = score; tclsf[oo] = clsf;
}

// ---------------- kernel 3: IoU>0.6 bitmask, upper-triangle units ----------------
#define SW(t) ((((t) & 31) << 3) | ((t) >> 5))
__global__ __launch_bounds__(64)
void mask_kernel(const float4* __restrict__ toff, const float* __restrict__ tarea,
                 u32* __restrict__ maskG) {
    #pragma clang fp contract(off)
    int u = blockIdx.x, b = blockIdx.y, tid = threadIdx.x;
    int g, wg;
    if (u < 128)      { g = u >> 2;                 wg = u & 3; }
    else if (u < 224) { int i2 = u - 128; g = 32 + i2 / 3;      wg = 1 + i2 % 3; }
    else if (u < 288) { int i2 = u - 224; g = 64 + (i2 >> 1);   wg = 2 + (i2 & 1); }
    else              { g = 96 + (u - 288);         wg = 3; }
    int i0 = g * 8, j0 = wg * 256;

    __shared__ float cx1[256], cy1[256], cx2[256], cy2[256], ca[256];
    for (int t = tid; t < 256; t += 64) {
        float4 f = toff[(size_t)b * KPAD + j0 + t];
        int ts = SW(t);
        cx1[ts] = f.x; cy1[ts] = f.y; cx2[ts] = f.z; cy2[ts] = f.w;
        ca[ts] = tarea[(size_t)b * KPAD + j0 + t];
    }
    __syncthreads();

    int ir = tid >> 3, wr = tid & 7;
    int i = i0 + ir;
    float4 fi = toff[(size_t)b * KPAD + i];
    float ai = tarea[(size_t)b * KPAD + i];
    u32 bits = 0;
    int jb = wr * 32;
    for (int jj = 0; jj < 32; ++jj) {
        int js = SW(jb + jj);
        float iw = fminf(fi.z, cx2[js]) - fmaxf(fi.x, cx1[js]) + 1.0f;
        iw = fmaxf(iw, 0.0f);
        float ih = fminf(fi.w, cy2[js]) - fmaxf(fi.y, cy1[js]) + 1.0f;
        ih = fmaxf(ih, 0.0f);
        float inter = iw * ih;
        float denom = (ai + ca[js]) - inter;
        float iou = inter / denom;
        bits |= (iou > 0.6f) ? (1u << jj) : 0u;
    }
    maskG[((size_t)b * KPAD + i) * 32 + wg * 8 + wr] = bits;
}

// ---------------- kernel 4: stage mask to LDS, 1-wave greedy scan, outputs ----------------
__global__ __launch_bounds__(512)
void scan_out_kernel(const u32* __restrict__ maskG, const u32* __restrict__ validbits,
                     const float4* __restrict__ traw, const float* __restrict__ tscore,
                     const float* __restrict__ tclsf, float* __restrict__ out) {
    __shared__ u32 sm[KPAD * 32];   // 128KB mask copy
    __shared__ u32 keeps[32];
    int b = blockIdx.x, tid = threadIdx.x;

    const uint4* s4 = (const uint4*)(maskG + (size_t)b * KPAD * 32);
    uint4* d4 = (uint4*)sm;
    #pragma unroll
    for (int r = 0; r < 16; ++r) d4[tid + r * 512] = s4[tid + r * 512];
    __syncthreads();

    if (tid < 64) {
        int lane = tid, lw = lane & 31;
        u32 vreg = (lane < 32) ? validbits[b * 32 + lane] : 0u;
        u32 removed = 0u, keepw = 0u;
        u32 mA[8], mB[8];
        #pragma unroll
        for (int d = 0; d < 8; ++d) {
            mA[d] = sm[d * 32 + lw];
            mB[d] = sm[(d + 8) * 32 + lw];
        }
        auto step8 = [&](int base, u32* ms) {
            #pragma unroll
            for (int d = 0; d < 8; ++d) {
                int i = base + d;
                int wi = i >> 5, bi2 = i & 31;
                u32 rw = (u32)__builtin_amdgcn_readlane((int)removed, wi);
                u32 vw = (u32)__builtin_amdgcn_readlane((int)vreg, wi);
                u32 k = ((vw >> bi2) & 1u) & (~(rw >> bi2) & 1u);
                if (k) removed |= ms[d];
                if (lane == wi) keepw |= (k << bi2);
                ms[d] = sm[(i + 16) * 32 + lw];
            }
        };
        for (int t = 0; t < 62; ++t) { step8(t * 16, mA); step8(t * 16 + 8, mB); }
        step8(992, mA);
        if (lane < 32) keeps[lane] = keepw;
    }
    __syncthreads();

    const int BQ = BATCH * MAXD;
    for (int s2 = tid; s2 < MAXD; s2 += 512) {
        u32 kf = (keeps[s2 >> 5] >> (s2 & 31)) & 1u;
        size_t oo = (size_t)b * KPAD + s2;
        float score = tscore[oo];
        float clsf = tclsf[oo];
        float4 bx = traw[oo];
        float x1 = fminf(fmaxf(bx.x, 0.f), 1279.f);
        float y1 = fminf(fmaxf(bx.y, 0.f), 1023.f);
        float x2 = fminf(fmaxf(bx.z, 0.f), 1279.f);
        float y2 = fminf(fmaxf(bx.w, 0.f), 1023.f);
        int base = b * MAXD + s2;
        out[base] = kf ? score : 0.0f;
        out[BQ + base] = kf ? clsf : 0.0f;
        float* ob = out + 2 * BQ + (size_t)base * 4;
        ob[0] = kf ? x1 : 0.f; ob[1] = kf ? y1 : 0.f;
        ob[2] = kf ? x2 : 0.f; ob[3] = kf ? y2 : 0.f;
        out[6 * BQ + base] = kf ? 1.0f : 0.0f;
    }
}

// ---------------- launch (4 nodes, no memsets) ----------------
extern "C" void kernel_launch(void* const* d_in, const int* in_sizes, int n_in,
                              void* d_out, int out_size, void* d_ws, size_t ws_size,
                              hipStream_t stream) {
    Ptrs ptrs;
    for (int i = 0; i < 30; ++i) ptrs.p[i] = (const float*)d_in[i];

    char* ws = (char*)d_ws;
    u64*    keyAll    = (u64*)   (ws + OFF_KEY);
    float4* traw      = (float4*)(ws + OFF_TRAW);
    float4* toff      = (float4*)(ws + OFF_TOFF);
    float*  tarea     = (float*) (ws + OFF_TAREA);
    float*  tscore    = (float*) (ws + OFF_TSCORE);
    float*  tclsf     = (float*) (ws + OFF_TCLSF);
    u32*    validbits = (u32*)   (ws + OFF_VALID);
    u32*    maskG     = (u32*)   (ws + OFF_MASK);
    float*  out       = (float*)d_out;

    decode_kernel<<<dim3(64, BATCH), 256, 0, stream>>>(ptrs, keyAll);
    select_gather_kernel<<<BATCH, 1024, 0, stream>>>(ptrs, keyAll, traw, toff, tarea,
                                                     tscore, tclsf, validbits);
    mask_kernel<<<dim3(320, BATCH), 64, 0, stream>>>(toff, tarea, maskG);
    scan_out_kernel<<<BATCH, 512, 0, stream>>>(maskG, validbits, traw, tscore, tclsf, out);
}

// Round 10
// 253.158 us; speedup vs baseline: 1.1243x; 1.1243x over previous
//
#include <hip/hip_runtime.h>
#include <hip/hip_bf16.h>

typedef unsigned long long u64;
typedef unsigned int u32;

#define NTOT    54560   // anchors per batch (r + i)
#define NMOD    27280   // anchors per modality
#define BATCH   16
#define KPAD    1024
#define MAXD    1000
#define NBIN    16384   // score-bits >> 16
#define CAND    6144    // LDS candidate cap (u64, 48KB)

struct Ptrs { const float* p[30]; };

// ---------------- workspace layout (16B aligned) ----------------
constexpr size_t SZ_KEY   = (size_t)BATCH * NTOT * 8;        // 6.98 MB
constexpr size_t SZ_TOPK  = (size_t)BATCH * KPAD * 8;
constexpr size_t SZ_TRAW  = (size_t)BATCH * KPAD * 16;
constexpr size_t SZ_T1    = (size_t)BATCH * KPAD * 4;
constexpr size_t SZ_MAXC  = (size_t)BATCH * 32 * 4;
constexpr size_t SZ_VALID = (size_t)BATCH * 32 * 4;
constexpr size_t SZ_MASK  = (size_t)BATCH * KPAD * 32 * 4;   // 2 MB

constexpr size_t OFF_KEY    = 0;
constexpr size_t OFF_TOPK   = OFF_KEY   + SZ_KEY;
constexpr size_t OFF_TRAW   = OFF_TOPK  + SZ_TOPK;
constexpr size_t OFF_TSCORE = OFF_TRAW  + SZ_TRAW;
constexpr size_t OFF_TCLSF  = OFF_TSCORE+ SZ_T1;
constexpr size_t OFF_MAXC   = OFF_TCLSF + SZ_T1;
constexpr size_t OFF_VALID  = OFF_MAXC  + SZ_MAXC;
constexpr size_t OFF_MASK   = OFF_VALID + SZ_VALID;

__device__ inline void level_of(int nm, int& l, int& pos, int& w, int& s, int& hw) {
    if (nm < 20480)      { l = 0; pos = nm;         w = 160; s = 8;   hw = 20480; }
    else if (nm < 25600) { l = 1; pos = nm - 20480; w = 80;  s = 16;  hw = 5120; }
    else if (nm < 26880) { l = 2; pos = nm - 25600; w = 40;  s = 32;  hw = 1280; }
    else if (nm < 27200) { l = 3; pos = nm - 26880; w = 20;  s = 64;  hw = 320; }
    else                 { l = 4; pos = nm - 27200; w = 10;  s = 128; hw = 80; }
}

__device__ inline float sigm(float x) { return 1.0f / (1.0f + expf(-x)); }

// async global->LDS DMA, 16B per lane; LDS dest = uniform base + lane*16
__device__ inline void ld_lds16(const float* g, float* l) {
    __builtin_amdgcn_global_load_lds(
        (const __attribute__((address_space(1))) void*)g,
        (__attribute__((address_space(3))) void*)l, 16, 0, 0);
}

// ---------------- kernel 1: decode (512-anchor LDS chunks + quad-split tail) ----------------
// 42KB LDS/block -> 3 blocks/CU resident (vs 1 at 84KB): staging of one block
// overlaps compute of another, removing the round-robin bubbles.
__global__ __launch_bounds__(128)
void decode_kernel(Ptrs ptrs, u64* __restrict__ keyAll) {
    __shared__ float lds[21 * 512];     // 42KB (unused by tail blocks)
    int cc = blockIdx.x;                // 0..99 LDS path, 100..126 tail
    int b = blockIdx.y;

    if (cc >= 100) {
        int t = (cc - 100) * 128 + threadIdx.x;   // 0..3359
        if (t >= 3360) return;
        int mod = t / 1680;
        int tm = t % 1680;
        int q = t & 3;                            // 1680 % 4 == 0
        int nm = 25600 + (tm & ~3);
        int l, pos, w, s, hw;
        level_of(nm, l, pos, w, s, hw);
        (void)w; (void)s;
        const float* clsP = ptrs.p[mod * 15 + l];
        const float* cntP = ptrs.p[mod * 15 + 5 + l];
        const float4* cb = (const float4*)(clsP + (size_t)b * 20 * hw + pos);
        int hw4 = hw >> 2;
        int c0 = q * 5;
        float4 v[5];
        #pragma unroll
        for (int c = 0; c < 5; ++c) v[c] = cb[(size_t)(c0 + c) * hw4];
        float4 cv = *(const float4*)(cntP + (size_t)b * hw + pos);
        float4 mx = v[0];
        #pragma unroll
        for (int c = 1; c < 5; ++c) {
            mx.x = fmaxf(mx.x, v[c].x); mx.y = fmaxf(mx.y, v[c].y);
            mx.z = fmaxf(mx.z, v[c].z); mx.w = fmaxf(mx.w, v[c].w);
        }
        mx.x = fmaxf(mx.x, __shfl_xor(mx.x, 1));
        mx.y = fmaxf(mx.y, __shfl_xor(mx.y, 1));
        mx.z = fmaxf(mx.z, __shfl_xor(mx.z, 1));
        mx.w = fmaxf(mx.w, __shfl_xor(mx.w, 1));
        mx.x = fmaxf(mx.x, __shfl_xor(mx.x, 2));
        mx.y = fmaxf(mx.y, __shfl_xor(mx.y, 2));
        mx.z = fmaxf(mx.z, __shfl_xor(mx.z, 2));
        mx.w = fmaxf(mx.w, __shfl_xor(mx.w, 2));
        float ma = (q & 1) ? ((q & 2) ? mx.w : mx.y) : ((q & 2) ? mx.z : mx.x);
        float ca = (q & 1) ? ((q & 2) ? cv.w : cv.y) : ((q & 2) ? cv.z : cv.x);
        u32 sb = __float_as_uint(sqrtf(__fmul_rn(sigm(ma), sigm(ca))));
        int n = mod * NMOD + nm + q;
        keyAll[(size_t)b * NTOT + n] = ((u64)sb << 16) | (u64)(65535 - n);
        return;
    }

    int mod = cc / 50, c = cc % 50;
    int l     = (c < 40) ? 0 : 1;
    int hw    = (c < 40) ? 20480 : 5120;
    int pos0  = (c < 40) ? c * 512 : (c - 40) * 512;
    int nmb   = (l == 0) ? pos0 : 20480 + pos0;
    const float* clsP = ptrs.p[mod * 15 + l];
    const float* cntP = ptrs.p[mod * 15 + 5 + l];
    int wave = threadIdx.x >> 6, lane = threadIdx.x & 63;

    const float* cbase = clsP + (size_t)b * 20 * hw + pos0 + wave * 256 + lane * 4;
    float* dbase = lds + wave * 256;
    #pragma unroll
    for (int ch = 0; ch < 20; ++ch)
        ld_lds16(cbase + (size_t)ch * hw, dbase + ch * 512);
    ld_lds16(cntP + (size_t)b * hw + pos0 + wave * 256 + lane * 4, dbase + 20 * 512);
    __syncthreads();

    int t = threadIdx.x;                 // 0..127, anchor group pos0 + 4t
    const float4* l4 = (const float4*)lds;
    float4 mx = l4[t];
    #pragma unroll
    for (int ch = 1; ch < 20; ++ch) {
        float4 v = l4[ch * 128 + t];
        mx.x = fmaxf(mx.x, v.x); mx.y = fmaxf(mx.y, v.y);
        mx.z = fmaxf(mx.z, v.z); mx.w = fmaxf(mx.w, v.w);
    }
    float4 cv = l4[20 * 128 + t];

    int n = mod * NMOD + nmb + t * 4;
    u32 s0 = __float_as_uint(sqrtf(__fmul_rn(sigm(mx.x), sigm(cv.x))));
    u32 s1 = __float_as_uint(sqrtf(__fmul_rn(sigm(mx.y), sigm(cv.y))));
    u32 s2 = __float_as_uint(sqrtf(__fmul_rn(sigm(mx.z), sigm(cv.z))));
    u32 s3 = __float_as_uint(sqrtf(__fmul_rn(sigm(mx.w), sigm(cv.w))));
    ulonglong2* ka2 = (ulonglong2*)(keyAll + (size_t)b * NTOT + n);
    ulonglong2 k01, k23;
    k01.x = ((u64)s0 << 16) | (u64)(65535 - n);
    k01.y = ((u64)s1 << 16) | (u64)(65535 - (n + 1));
    k23.x = ((u64)s2 << 16) | (u64)(65535 - (n + 2));
    k23.y = ((u64)s3 << 16) | (u64)(65535 - (n + 3));
    ka2[0] = k01; ka2[1] = k23;
}

// ---------------- kernel 2: select (hist + B1 + bucket scatter + in-bin fixup) ----------------
__global__ __launch_bounds__(1024)
void select_kernel(const u64* __restrict__ keyAll, u64* __restrict__ topkey,
                   u32* __restrict__ maxcG) {
    int b = blockIdx.x, tid = threadIdx.x;
    int lane = tid & 63, wid = tid >> 6;
    __shared__ u32 shist[NBIN];        // 64KB: counts -> prefixes -> segment ends
    __shared__ u64 scand[CAND];        // 48KB bin-ordered candidates
    __shared__ u64 stopk[KPAD];        // 8KB sorted top keys
    __shared__ u32 warep[16];
    __shared__ int sB1;

    if (tid == 0) maxcG[b * 32] = 0u;  // gather's atomicMax baseline
    #pragma unroll
    for (int j = 0; j < NBIN / 1024; ++j) shist[tid + j * 1024] = 0u;
    __syncthreads();

    const u64* keys = keyAll + (size_t)b * NTOT;
    const u64 SENT = ~0ull;
    // phase 1: LDS histogram
    for (int n0 = 0; n0 < NTOT; n0 += 8192) {
        u64 kk[8];
        #pragma unroll
        for (int r = 0; r < 8; ++r) {
            int idx = n0 + r * 1024 + tid;
            kk[r] = (idx < NTOT) ? keys[idx] : SENT;
        }
        #pragma unroll
        for (int r = 0; r < 8; ++r)
            if (kk[r] != SENT) atomicAdd(&shist[(u32)(kk[r] >> 32)], 1u);
    }
    __syncthreads();

    // phase 2: reverse scan -> B1; write P[bin] (count of keys in bins > bin) back
    u32 loc[16]; u32 sum = 0;
    #pragma unroll
    for (int j = 0; j < 16; ++j) { loc[j] = shist[NBIN - 1 - (tid * 16 + j)]; sum += loc[j]; }
    u32 v = sum;
    #pragma unroll
    for (int off = 1; off < 64; off <<= 1) {
        u32 t2 = (u32)__shfl_up((int)v, off);
        if (lane >= off) v += t2;
    }
    if (lane == 63) warep[wid] = v;
    __syncthreads();
    if (tid < 16) {
        u32 p = warep[tid];
        #pragma unroll
        for (int off = 1; off < 16; off <<= 1) {
            u32 t2 = (u32)__shfl_up((int)p, off);
            if (tid >= off) p += t2;
        }
        warep[tid] = p;
    }
    __syncthreads();
    u32 incl = v + (wid ? warep[wid - 1] : 0u);
    u32 excl = incl - sum;
    if (excl < (u32)MAXD && incl >= (u32)MAXD) {
        u32 c = excl;
        #pragma unroll
        for (int j = 0; j < 16; ++j) {
            c += loc[j];
            if (c >= (u32)MAXD) { sB1 = NBIN - 1 - (tid * 16 + j); break; }
        }
    }
    u32 run = excl;
    #pragma unroll
    for (int j = 0; j < 16; ++j) {
        int bin = NBIN - 1 - (tid * 16 + j);
        shist[bin] = run;
        run += loc[j];
    }
    __syncthreads();
    int B1 = sB1;

    // phase 3: scatter candidates to bin-ordered positions
    for (int n0 = 0; n0 < NTOT; n0 += 8192) {
        u64 kk[8];
        #pragma unroll
        for (int r = 0; r < 8; ++r) {
            int idx = n0 + r * 1024 + tid;
            kk[r] = (idx < NTOT) ? keys[idx] : 0ull;   // real keys never 0
        }
        #pragma unroll
        for (int r = 0; r < 8; ++r) {
            if (kk[r] != 0ull && (int)(kk[r] >> 32) >= B1) {
                u32 p = atomicAdd(&shist[(u32)(kk[r] >> 32)], 1u);
                if (p < CAND) scand[p] = kk[r];
            }
        }
    }
    __syncthreads();
    int Ctot = min((int)shist[B1], CAND);

    // phase 4: in-bin rank fixup -> exact sorted positions
    for (int i = tid; i < Ctot; i += 1024) {
        u64 ki = scand[i];
        int bin = (int)(ki >> 32);
        int st = (int)shist[bin + 1];              // segment start
        int en = min((int)shist[bin], Ctot);       // segment end
        int pos = st;
        for (int j = st; j < en; ++j) pos += (scand[j] > ki) ? 1 : 0;
        if (pos < MAXD) stopk[pos] = ki;
    }
    __syncthreads();
    if (tid < MAXD) topkey[(size_t)b * KPAD + tid] = stopk[tid];
}

// ---------------- kernel 3: gather winners (wide, pair-split channels) ----------------
__global__ __launch_bounds__(128)
void gather_kernel(Ptrs ptrs, const u64* __restrict__ topkey,
                   float4* __restrict__ traw, float* __restrict__ tscore,
                   float* __restrict__ tclsf, u32* __restrict__ validwords,
                   u32* __restrict__ maxcG) {
    #pragma clang fp contract(off)
    int b = blockIdx.y;
    int tid = threadIdx.x;
    int half = tid & 1;
    int i = blockIdx.x * 64 + (tid >> 1);
    int active = (i < MAXD);

    float score = 0.f;
    float best = -1.0f; int bi = 0;
    float ra = 0.f, rb2 = 0.f;
    int pos = 0, w = 1, s = 0;
    if (active) {
        u64 key = topkey[(size_t)b * KPAD + i];
        int n = 65535 - (int)(key & 0xFFFFull);
        score = __uint_as_float((u32)(key >> 16));
        int mod = (n >= NMOD) ? 1 : 0;
        int nm = n - mod * NMOD;
        int l, hw;
        level_of(nm, l, pos, w, s, hw);
        const float* clsP = ptrs.p[mod * 15 + l];
        const float* regP = ptrs.p[mod * 15 + 10 + l];
        const float* cbp = clsP + (size_t)b * 20 * hw + pos;
        const float* rbp = regP + (size_t)b * 4 * hw + pos;
        float cl[10];
        int c0 = half * 10;
        #pragma unroll
        for (int c = 0; c < 10; ++c) cl[c] = cbp[(size_t)(c0 + c) * hw];
        ra  = rbp[(size_t)(half * 2) * hw];
        rb2 = rbp[(size_t)(half * 2 + 1) * hw];
        #pragma unroll
        for (int c = 0; c < 10; ++c) {
            float p = sigm(cl[c]);
            if (p > best) { best = p; bi = c0 + c; }
        }
    }
    float po  = __shfl_xor(best, 1);
    int   bio = __shfl_xor(bi, 1);
    float rao = __shfl_xor(ra, 1);
    float rbo = __shfl_xor(rb2, 1);
    if (half == 0) { if (po > best)  { best = po; bi = bio; } }
    else           { if (po >= best) { best = po; bi = bio; } }
    float clsf = active ? (float)(bi + 1) : 0.f;
    float r0 = half ? rao : ra,  r1 = half ? rbo : rb2;
    float r2 = half ? ra  : rao, r3 = half ? rb2 : rbo;

    float4 bx = make_float4(0.f, 0.f, 0.f, 0.f);
    if (active) {
        int xi = pos % w, yi = pos / w;
        float cx = (float)(xi * s + (s >> 1));
        float cy = (float)(yi * s + (s >> 1));
        bx.x = cx - r0; bx.y = cy - r1; bx.z = cx + r2; bx.w = cy + r3;
    }
    int valid = active && (score >= 0.05f) && (half == 0);
    float contrib = valid ? fmaxf(0.0f, fmaxf(fmaxf(bx.x, bx.y), fmaxf(bx.z, bx.w))) : 0.0f;
    float red = contrib;
    #pragma unroll
    for (int off = 32; off > 0; off >>= 1) red = fmaxf(red, __shfl_down(red, off));
    if ((tid & 63) == 0) atomicMax(&maxcG[b * 32], __float_as_uint(red));
    u64 ball = __ballot(valid != 0);
    if ((tid & 63) == 0) {
        u32 word = 0;
        for (int j = 0; j < 32; ++j) word |= (u32)((ball >> (2 * j)) & 1ull) << j;
        validwords[b * 32 + blockIdx.x * 2 + (tid >> 6)] = word;
    }
    if (half == 0) {
        size_t oo = (size_t)b * KPAD + i;
        traw[oo] = bx; tscore[oo] = score; tclsf[oo] = clsf;   // zeros for i >= MAXD
    }
}

// ---------------- kernel 4: IoU>0.6 bitmask (256-thread units, upper-triangle) ----------------
// unit = 32 rows x 256 cols; 80/128 units per batch survive the triangle skip.
// offset boxes + areas recomputed inline (bit-identical expressions).
#define SW(t) ((((t) & 31) << 3) | ((t) >> 5))
__global__ __launch_bounds__(256)
void mask_kernel(const float4* __restrict__ traw, const float* __restrict__ tclsf,
                 const u32* __restrict__ maxcG, u32* __restrict__ maskG) {
    #pragma clang fp contract(off)
    int u = blockIdx.x, b = blockIdx.y, tid = threadIdx.x;
    int g, wg;
    if (u < 32)      { g = u >> 2;              wg = u & 3; }
    else if (u < 56) { int d = u - 32; g = 8  + d / 3;        wg = 1 + d % 3; }
    else if (u < 72) { int d = u - 56; g = 16 + (d >> 1);     wg = 2 + (d & 1); }
    else             { g = 24 + (u - 72);       wg = 3; }
    int i0 = g * 32, j0 = wg * 256;
    float m1 = __uint_as_float(maxcG[b * 32]) + 1.0f;

    __shared__ float cx1[256], cy1[256], cx2[256], cy2[256], ca[256];
    {
        int t = tid;
        float4 f = traw[(size_t)b * KPAD + j0 + t];
        float o = __fmul_rn(tclsf[(size_t)b * KPAD + j0 + t], m1);
        float ox1 = __fadd_rn(f.x, o), oy1 = __fadd_rn(f.y, o);
        float ox2 = __fadd_rn(f.z, o), oy2 = __fadd_rn(f.w, o);
        float dw = ox2 - ox1 + 1.0f;
        float dh = oy2 - oy1 + 1.0f;
        int ts = SW(t);
        cx1[ts] = ox1; cy1[ts] = oy1; cx2[ts] = ox2; cy2[ts] = oy2;
        ca[ts] = __fmul_rn(dw, dh);
    }
    __syncthreads();

    int ir = tid >> 3, wr = tid & 7;
    int i = i0 + ir;
    float4 fi = traw[(size_t)b * KPAD + i];
    float oi = __fmul_rn(tclsf[(size_t)b * KPAD + i], m1);
    float ix1 = __fadd_rn(fi.x, oi), iy1 = __fadd_rn(fi.y, oi);
    float ix2 = __fadd_rn(fi.z, oi), iy2 = __fadd_rn(fi.w, oi);
    float dwi = ix2 - ix1 + 1.0f, dhi = iy2 - iy1 + 1.0f;
    float ai = __fmul_rn(dwi, dhi);
    u32 bits = 0;
    int jb = wr * 32;
    for (int jj = 0; jj < 32; ++jj) {
        int js = SW(jb + jj);
        float iw = fminf(ix2, cx2[js]) - fmaxf(ix1, cx1[js]) + 1.0f;
        iw = fmaxf(iw, 0.0f);
        float ih = fminf(iy2, cy2[js]) - fmaxf(iy1, cy1[js]) + 1.0f;
        ih = fmaxf(ih, 0.0f);
        float inter = iw * ih;
        float denom = (ai + ca[js]) - inter;
        float iou = inter / denom;
        bits |= (iou > 0.6f) ? (1u << jj) : 0u;
    }
    maskG[((size_t)b * KPAD + i) * 32 + wg * 8 + wr] = bits;
}

// ---------------- kernel 5: stage mask to LDS, 1-wave greedy scan, outputs ----------------
__global__ __launch_bounds__(512)
void scan_out_kernel(const u32* __restrict__ maskG, const u32* __restrict__ validbits,
                     const float4* __restrict__ traw, const float* __restrict__ tscore,
                     const float* __restrict__ tclsf, float* __restrict__ out) {
    __shared__ u32 sm[KPAD * 32];   // 128KB mask copy
    __shared__ u32 keeps[32];
    int b = blockIdx.x, tid = threadIdx.x;

    const uint4* s4 = (const uint4*)(maskG + (size_t)b * KPAD * 32);
    uint4* d4 = (uint4*)sm;
    #pragma unroll
    for (int r = 0; r < 16; ++r) d4[tid + r * 512] = s4[tid + r * 512];
    __syncthreads();

    if (tid < 64) {
        int lane = tid, lw = lane & 31;
        u32 vreg = (lane < 32) ? validbits[b * 32 + lane] : 0u;
        u32 removed = 0u, keepw = 0u;
        u32 mA[8], mB[8];
        #pragma unroll
        for (int d = 0; d < 8; ++d) {
            mA[d] = sm[d * 32 + lw];
            mB[d] = sm[(d + 8) * 32 + lw];
        }
        auto step8 = [&](int base, u32* ms) {
            #pragma unroll
            for (int d = 0; d < 8; ++d) {
                int i = base + d;
                int wi = i >> 5, bi2 = i & 31;
                u32 rw = (u32)__builtin_amdgcn_readlane((int)removed, wi);
                u32 vw = (u32)__builtin_amdgcn_readlane((int)vreg, wi);
                u32 k = ((vw >> bi2) & 1u) & (~(rw >> bi2) & 1u);
                if (k) removed |= ms[d];
                if (lane == wi) keepw |= (k << bi2);
                ms[d] = sm[(i + 16) * 32 + lw];
            }
        };
        for (int t = 0; t < 62; ++t) { step8(t * 16, mA); step8(t * 16 + 8, mB); }
        step8(992, mA);
        if (lane < 32) keeps[lane] = keepw;
    }
    __syncthreads();

    const int BQ = BATCH * MAXD;
    for (int s2 = tid; s2 < MAXD; s2 += 512) {
        u32 kf = (keeps[s2 >> 5] >> (s2 & 31)) & 1u;
        size_t oo = (size_t)b * KPAD + s2;
        float score = tscore[oo];
        float clsf = tclsf[oo];
        float4 bx = traw[oo];
        float x1 = fminf(fmaxf(bx.x, 0.f), 1279.f);
        float y1 = fminf(fmaxf(bx.y, 0.f), 1023.f);
        float x2 = fminf(fmaxf(bx.z, 0.f), 1279.f);
        float y2 = fminf(fmaxf(bx.w, 0.f), 1023.f);
        int base = b * MAXD + s2;
        out[base] = kf ? score : 0.0f;
        out[BQ + base] = kf ? clsf : 0.0f;
        float* ob = out + 2 * BQ + (size_t)base * 4;
        ob[0] = kf ? x1 : 0.f; ob[1] = kf ? y1 : 0.f;
        ob[2] = kf ? x2 : 0.f; ob[3] = kf ? y2 : 0.f;
        out[6 * BQ + base] = kf ? 1.0f : 0.0f;
    }
}

// ---------------- launch (5 nodes, no memsets) ----------------
extern "C" void kernel_launch(void* const* d_in, const int* in_sizes, int n_in,
                              void* d_out, int out_size, void* d_ws, size_t ws_size,
                              hipStream_t stream) {
    Ptrs ptrs;
    for (int i = 0; i < 30; ++i) ptrs.p[i] = (const float*)d_in[i];

    char* ws = (char*)d_ws;
    u64*    keyAll    = (u64*)   (ws + OFF_KEY);
    u64*    topkey    = (u64*)   (ws + OFF_TOPK);
    float4* traw      = (float4*)(ws + OFF_TRAW);
    float*  tscore    = (float*) (ws + OFF_TSCORE);
    float*  tclsf     = (float*) (ws + OFF_TCLSF);
    u32*    maxcG     = (u32*)   (ws + OFF_MAXC);
    u32*    validbits = (u32*)   (ws + OFF_VALID);
    u32*    maskG     = (u32*)   (ws + OFF_MASK);
    float*  out       = (float*)d_out;

    decode_kernel<<<dim3(127, BATCH), 128, 0, stream>>>(ptrs, keyAll);
    select_kernel<<<BATCH, 1024, 0, stream>>>(keyAll, topkey, maxcG);
    gather_kernel<<<dim3(16, BATCH), 128, 0, stream>>>(ptrs, topkey, traw, tscore, tclsf,
                                                       validbits, maxcG);
    mask_kernel<<<dim3(80, BATCH), 256, 0, stream>>>(traw, tclsf, maxcG, maskG);
    scan_out_kernel<<<BATCH, 512, 0, stream>>>(maskG, validbits, traw, tscore, tclsf, out);
}